// Round 3
// baseline (226.635 us; speedup 1.0000x reference)
//
#include <hip/hip_runtime.h>
#include <string.h>

// Integrate-and-fire scan: x_seq (T=64, 128, 4096) f32 -> s_seq same shape.
//   v += x[t]; s = (v >= 1.0f); v -= s;
// Latency-bound history: R1 2.5 TB/s (VGPR=32, ~1 load in flight), R2 identical
// (VGPR=16: compiler sank the "double buffer" loads to just-before-use).
// R3: __builtin_amdgcn_sched_barrier(0) fences pin [load batch k+1] apart from
// [consume batch k + store], forcing 8 loads in flight per wave.

#define TSTEPS 64
#define NCOLS  (128 * 4096)    // 524288 columns
#define NCOLS2 (NCOLS / 2)     // 262144 float2 column-groups
#define BATCH  8               // loads in flight per wave

__global__ __launch_bounds__(256) void TandemIF_86096914416163_kernel(
    const float2* __restrict__ x, float2* __restrict__ out)
{
    const int c = blockIdx.x * 256 + threadIdx.x;   // grid sized exactly
    const float2* xp = x   + c;
    float2*       op = out + c;

    float vx = 0.0f, vy = 0.0f;
    float2 cur[BATCH], nxt[BATCH];

    // Prime: batch 0 in flight.
#pragma unroll
    for (int j = 0; j < BATCH; ++j)
        cur[j] = xp[j * NCOLS2];
    __builtin_amdgcn_sched_barrier(0);   // nothing crosses: loads stay issued

#pragma unroll
    for (int tb = 0; tb < TSTEPS / BATCH; ++tb) {
        // Issue next batch BEFORE this batch's stores: the wait for cur[] data
        // then never waits on anything newer (in-order vmcnt retirement).
        if (tb + 1 < TSTEPS / BATCH) {
#pragma unroll
            for (int j = 0; j < BATCH; ++j)
                nxt[j] = xp[((tb + 1) * BATCH + j) * NCOLS2];
        }
        __builtin_amdgcn_sched_barrier(0);   // loads may not sink past here

#pragma unroll
        for (int j = 0; j < BATCH; ++j) {
            const float2 xt = cur[j];
            vx += xt.x; vy += xt.y;
            const float sx = (vx >= 1.0f) ? 1.0f : 0.0f;
            const float sy = (vy >= 1.0f) ? 1.0f : 0.0f;
            vx -= sx; vy -= sy;
            float2 s = make_float2(sx, sy);
            // Non-temporal 8B store: write-once output; keep L2/L3 for x.
            double sbits;
            memcpy(&sbits, &s, sizeof(sbits));
            __builtin_nontemporal_store(
                sbits, reinterpret_cast<double*>(op + (tb * BATCH + j) * NCOLS2));
        }
        __builtin_amdgcn_sched_barrier(0);   // stores may not migrate up

        // Rotate register buffers (fully unrolled -> compiler renames, no movs).
#pragma unroll
        for (int j = 0; j < BATCH; ++j)
            cur[j] = nxt[j];
    }
}

extern "C" void kernel_launch(void* const* d_in, const int* in_sizes, int n_in,
                              void* d_out, int out_size, void* d_ws, size_t ws_size,
                              hipStream_t stream)
{
    const float2* x = (const float2*)d_in[0];
    float2* out     = (float2*)d_out;
    // 262144 float2 columns / 256 threads = 1024 blocks (4 blocks/CU, 16 waves/CU)
    TandemIF_86096914416163_kernel<<<dim3(NCOLS2 / 256), dim3(256), 0, stream>>>(x, out);
}

// Round 4
// 226.582 us; speedup vs baseline: 1.0002x; 1.0002x over previous
//
#include <hip/hip_runtime.h>
#include <string.h>

// Integrate-and-fire scan: x_seq (T=64, 128, 4096) f32 -> s_seq same shape.
//   v += x[t]; s = (v >= 1.0f); v -= s;
// History: R1-R3 stuck at 2.5 TB/s, latency-bound, MLP~1. Root cause found in
// R3: __launch_bounds__(256) with no min-waves arg -> backend targets MAX
// occupancy (<=32 VGPR), so the scheduler sinks every load to its use to save
// registers, even though occupancy is grid-limited at 16 waves/CU anyway.
// R4: __launch_bounds__(256, 4) = 16 waves/CU target -> 128-VGPR budget, so
// the 8-deep register pipeline can actually live in registers.

#define TSTEPS 64
#define NCOLS  (128 * 4096)    // 524288 columns
#define NCOLS2 (NCOLS / 2)     // 262144 float2 column-groups
#define BATCH  8               // loads in flight per wave

__global__ __launch_bounds__(256, 4) void TandemIF_86096914416163_kernel(
    const float2* __restrict__ x, float2* __restrict__ out)
{
    const int c = blockIdx.x * 256 + threadIdx.x;   // grid sized exactly
    const float2* xp = x   + c;
    float2*       op = out + c;

    float vx = 0.0f, vy = 0.0f;
    float2 cur[BATCH], nxt[BATCH];

    // Prime: batch 0 in flight.
#pragma unroll
    for (int j = 0; j < BATCH; ++j)
        cur[j] = xp[j * NCOLS2];
    __builtin_amdgcn_sched_barrier(0);

#pragma unroll
    for (int tb = 0; tb < TSTEPS / BATCH; ++tb) {
        // Issue next batch BEFORE this batch's consume+stores: in-order vmcnt
        // retirement means waiting on cur[] never waits on these.
        if (tb + 1 < TSTEPS / BATCH) {
#pragma unroll
            for (int j = 0; j < BATCH; ++j)
                nxt[j] = xp[((tb + 1) * BATCH + j) * NCOLS2];
        }
        __builtin_amdgcn_sched_barrier(0);   // loads may not sink past here

#pragma unroll
        for (int j = 0; j < BATCH; ++j) {
            const float2 xt = cur[j];
            vx += xt.x; vy += xt.y;
            const float sx = (vx >= 1.0f) ? 1.0f : 0.0f;
            const float sy = (vy >= 1.0f) ? 1.0f : 0.0f;
            vx -= sx; vy -= sy;
            float2 s = make_float2(sx, sy);
            // Non-temporal 8B store: write-once output; keep L2/L3 for x.
            double sbits;
            memcpy(&sbits, &s, sizeof(sbits));
            __builtin_nontemporal_store(
                sbits, reinterpret_cast<double*>(op + (tb * BATCH + j) * NCOLS2));
        }
        __builtin_amdgcn_sched_barrier(0);   // stores may not migrate up

        // Rotate register buffers (fully unrolled -> pure register renaming).
#pragma unroll
        for (int j = 0; j < BATCH; ++j)
            cur[j] = nxt[j];
    }
}

extern "C" void kernel_launch(void* const* d_in, const int* in_sizes, int n_in,
                              void* d_out, int out_size, void* d_ws, size_t ws_size,
                              hipStream_t stream)
{
    const float2* x = (const float2*)d_in[0];
    float2* out     = (float2*)d_out;
    // 262144 float2 columns / 256 threads = 1024 blocks (4 blocks/CU, 16 waves/CU)
    TandemIF_86096914416163_kernel<<<dim3(NCOLS2 / 256), dim3(256), 0, stream>>>(x, out);
}